// Round 10
// baseline (10385.027 us; speedup 1.0000x reference)
//
#include <hip/hip_runtime.h>

typedef unsigned short u16;
typedef unsigned long long u64;
typedef unsigned u32;
typedef __bf16 v8bf __attribute__((ext_vector_type(8)));
typedef float f32x4 __attribute__((ext_vector_type(4)));
typedef u16 u16x4 __attribute__((ext_vector_type(4)));
typedef u32 u32x4 __attribute__((ext_vector_type(4)));
typedef u32 u32x2 __attribute__((ext_vector_type(2)));

#define H5 1280
#define TT 512
#define NBLK 80
#define SPL 81920 // u16 elems per split buffer (64*1280)

// ws layout (bytes)
#define OFF_W0 0
#define OFF_W1 3276800
#define OFF_W2 6553600
#define OFF_HS 9830400   // u16 [2][3][64][1280]
#define OFF_WIN 10813440 // float [4][256]
#define OFF_CNT 10817536 // u32: word 128+g*32: group flag lines (10 slots each)

#define MFMA(a, b, c) __builtin_amdgcn_mfma_f32_16x16x32_bf16(a, b, c, 0, 0, 0)

__device__ __forceinline__ float htanh_(float x) {
  return fminf(fmaxf(x, 1e-10f), 1.0f);
}
__device__ __forceinline__ u16 f2b(float f) {
  unsigned u = __float_as_uint(f);
  return (u16)((u + 0x7fffu + ((u >> 16) & 1u)) >> 16);  // RNE
}
__device__ __forceinline__ float b2f(u16 b) {
  return __uint_as_float(((unsigned)b) << 16);
}
__device__ __forceinline__ u32 umin_(u32 a, u32 b) { return a < b ? a : b; }

// device-scope (sc1) 8B store: write-through to coherence point (r8-proven)
__device__ __forceinline__ void st8_sc1(u16* p, u16x4 v) {
  union { u16x4 s; u64 q; } u;
  u.s = v;
  asm volatile("global_store_dwordx2 %0, %1, off sc1" :: "v"(p), "v"(u.q) : "memory");
}

// ---------------- prep: effective W_rec, 3-way bf16 split -------------------
__global__ void build_w(const float* __restrict__ w_str2snr, const float* __restrict__ w_m12m1,
                        const float* __restrict__ w_m12str, const float* __restrict__ w_thal2m1,
                        const float* __restrict__ w_m12thal, const float* __restrict__ w_thal2str,
                        const float* __restrict__ w_str2stn, const float* __restrict__ w_snr2thal,
                        const float* __restrict__ fixedw, u16* __restrict__ W0,
                        u16* __restrict__ W1, u16* __restrict__ W2) {
  int idx = blockIdx.x * 256 + threadIdx.x;  // j*1280 + k
  if (idx >= H5 * H5) return;
  int j = idx / H5, k = idx - j * H5;
  int jr = j >> 8, kr = k >> 8, kk = k & 255;
  int o = (j & 255) * 256 + kk;
  float w = 0.0f;
  if (jr == 0) {
    if (kr == 0) w = -fixedw[o];
    else if (kr == 3) w = htanh_(w_thal2str[o]);
    else if (kr == 4) w = (kk < 180) ? htanh_(w_m12str[o]) : 0.0f;  // n_inhib=76
  } else if (jr == 1) {
    if (kr == 0) w = (kk >= 128) ? htanh_(w_str2stn[o]) : 0.0f;
  } else if (jr == 2) {
    if (kr == 0) w = (kk < 128) ? -htanh_(w_str2snr[o]) : 0.0f;
    else if (kr == 1) w = -htanh_(w_str2stn[o]);  // faithful: str2stn weight
  } else if (jr == 3) {
    if (kr == 2) w = -htanh_(w_snr2thal[o]);
    else if (kr == 4) w = htanh_(w_m12thal[o]);
  } else {
    if (kr == 3) w = htanh_(w_thal2m1[o]);
    else if (kr == 4) w = (kk < 180) ? htanh_(w_m12m1[o]) : -htanh_(w_m12m1[o]);
  }
  u16 c0 = f2b(w);  float r1 = w - b2f(c0);
  u16 c1 = f2b(r1); float r2 = r1 - b2f(c1);
  u16 c2 = f2b(r2);
  W0[idx] = c0; W1[idx] = c1; W2[idx] = c2;
}

// ---------------- prep: mean/std out, h0 splits, Win ------------------------
__global__ void build_misc(const float* __restrict__ hn, const float* __restrict__ inp_weight,
                           const float* __restrict__ mean_b, const float* __restrict__ std_b,
                           float* __restrict__ out, u16* __restrict__ hs, float* __restrict__ Win) {
  int gid = blockIdx.x * 256 + threadIdx.x;
  if (gid < 65536) {
    out[gid] = (gid < 32768) ? mean_b[0] : fminf(10.0f, fmaxf(-5.0f, std_b[0]));
  } else if (gid < 65536 + SPL) {
    int i = gid - 65536;
    float v = hn[i];
    u16 c0 = f2b(v);  float r1 = v - b2f(c0);
    u16 c1 = f2b(r1); float r2 = r1 - b2f(c1);
    u16 c2 = f2b(r2);
    hs[i] = c0; hs[SPL + i] = c1; hs[2 * SPL + i] = c2;
  } else if (gid < 65536 + SPL + 1024) {
    int i = gid - 65536 - SPL;
    Win[i] = htanh_(inp_weight[(i >> 8) * H5 + 768 + (i & 255)]);
  }
}

// ---------------- compile-time region configs -------------------------------
template <int R> struct RC;
template <> struct RC<0> { static constexpr int kb[3] = {0, 768, 1024}; static constexpr int nch[3] = {8, 8, 8}; };
template <> struct RC<1> { static constexpr int kb[3] = {128, 0, 0};    static constexpr int nch[3] = {4, 0, 0}; };
template <> struct RC<2> { static constexpr int kb[3] = {0, 256, 0};    static constexpr int nch[3] = {4, 8, 0}; };
template <> struct RC<3> { static constexpr int kb[3] = {512, 1024, 0}; static constexpr int nch[3] = {8, 8, 0}; };
template <> struct RC<4> { static constexpr int kb[3] = {768, 1024, 0}; static constexpr int nch[3] = {8, 8, 0}; };

// Stage this region's h union-span (8 cols x 3 splits) into LDS in ONE sc1
// burst: all loads issued back-to-back, single vmcnt(0), then ds_writes.
// LDS layout per q: [split*8+col][k], col stride = nch*32+8 u16 (bank pad).
template <int R>
__device__ __forceinline__ void stage_h(const u16* __restrict__ hs_r, int bcol0,
                                        u16* __restrict__ sm) {
  v8bf regs[9];
  int n = 0;
#pragma unroll
  for (int q = 0; q < 3; ++q) {
    if (RC<R>::nch[q] > 0) {
      const int span8 = RC<R>::nch[q] * 4;     // 16B units per (split,col)
      const int units = span8 * 24;            // 8 cols x 3 splits
      const int rounds = (units + 255) / 256;
#pragma unroll
      for (int r = 0; r < rounds; ++r) {
        int u = threadIdx.x + r * 256;
        if (u < units) {
          int kunit = u & (span8 - 1);         // span8 is 16 or 32 (pow2)
          int sc = u / span8;
          int split = sc >> 3, col = sc & 7;
          const u16* gp = hs_r + split * SPL + (long)(bcol0 + col) * H5 +
                          RC<R>::kb[q] + kunit * 8;
          asm volatile("global_load_dwordx4 %0, %1, off sc1"
                       : "=v"(regs[n]) : "v"(gp) : "memory");
        }
        ++n;
      }
    }
  }
  asm volatile("s_waitcnt vmcnt(0)" ::: "memory");
  __builtin_amdgcn_sched_barrier(0);
  n = 0;
  int base = 0;
#pragma unroll
  for (int q = 0; q < 3; ++q) {
    if (RC<R>::nch[q] > 0) {
      const int span8 = RC<R>::nch[q] * 4;
      const int colstride = RC<R>::nch[q] * 32 + 8;
      const int units = span8 * 24;
      const int rounds = (units + 255) / 256;
#pragma unroll
      for (int r = 0; r < rounds; ++r) {
        int u = threadIdx.x + r * 256;
        if (u < units) {
          int kunit = u & (span8 - 1);
          int sc = u / span8;
          *(v8bf*)(sm + base + sc * colstride + kunit * 8) = regs[n];
        }
        ++n;
      }
      base += 24 * colstride;
    }
  }
}

// One step's matmul for one wave's TWO j-tiles; B from LDS, A (W) from L2.
template <int R>
__device__ __forceinline__ void mm_lds(const u16* __restrict__ sm, int lk, int col,
                                       const u16* __restrict__ W0, const u16* __restrict__ W1,
                                       const u16* __restrict__ W2, long jrowA, long jrowB,
                                       f32x4 (&out)[2]) {
  f32x4 acc[2][6];
#pragma unroll
  for (int t = 0; t < 2; ++t)
#pragma unroll
    for (int s = 0; s < 6; ++s) acc[t][s] = {0.f, 0.f, 0.f, 0.f};
  int base = 0;
#pragma unroll
  for (int q = 0; q < 3; ++q) {
    if (RC<R>::nch[q] > 0) {
      const int kbq = RC<R>::kb[q];
      const int colstride = RC<R>::nch[q] * 32 + 8;
#pragma unroll
      for (int c = 0; c < RC<R>::nch[q]; ++c) {
        v8bf B0 = *(const v8bf*)(sm + base + (0 * 8 + col) * colstride + c * 32 + lk);
        v8bf B1 = *(const v8bf*)(sm + base + (1 * 8 + col) * colstride + c * 32 + lk);
        v8bf B2 = *(const v8bf*)(sm + base + (2 * 8 + col) * colstride + c * 32 + lk);
        long oA = jrowA + kbq + c * 32, oB = jrowB + kbq + c * 32;
        v8bf a0 = *(const v8bf*)(W0 + oA);
        v8bf a1 = *(const v8bf*)(W1 + oA);
        v8bf a2 = *(const v8bf*)(W2 + oA);
        v8bf b0 = *(const v8bf*)(W0 + oB);
        v8bf b1 = *(const v8bf*)(W1 + oB);
        v8bf b2 = *(const v8bf*)(W2 + oB);
        // 6-term split product per tile: W0h0+W0h1+W0h2 + W1h0+W1h1 + W2h0
        acc[0][0] = MFMA(a0, B0, acc[0][0]);
        acc[1][0] = MFMA(b0, B0, acc[1][0]);
        acc[0][1] = MFMA(a0, B1, acc[0][1]);
        acc[1][1] = MFMA(b0, B1, acc[1][1]);
        acc[0][2] = MFMA(a0, B2, acc[0][2]);
        acc[1][2] = MFMA(b0, B2, acc[1][2]);
        acc[0][3] = MFMA(a1, B0, acc[0][3]);
        acc[1][3] = MFMA(b1, B0, acc[1][3]);
        acc[0][4] = MFMA(a1, B1, acc[0][4]);
        acc[1][4] = MFMA(b1, B1, acc[1][4]);
        acc[0][5] = MFMA(a2, B0, acc[0][5]);
        acc[1][5] = MFMA(b2, B0, acc[1][5]);
      }
      base += 24 * colstride;
    }
  }
#pragma unroll
  for (int t = 0; t < 2; ++t)
#pragma unroll
    for (int rr = 0; rr < 4; ++rr)
      out[t][rr] = ((acc[t][0][rr] + acc[t][3][rr]) + (acc[t][1][rr] + acc[t][4][rr])) +
                   (acc[t][2][rr] + acc[t][5][rr]);
}

// ---------------- persistent worker (r8 geometry, shortened sync chain) -----
template <int R>
__device__ void pers_loop(int j0, int bcol, bool act, int hi, int lk, int lr, int bcol0,
                          const float* __restrict__ inp_b, const float* __restrict__ hn,
                          const u16* __restrict__ W0, const u16* __restrict__ W1,
                          const u16* __restrict__ W2, u16* __restrict__ hs,
                          float* __restrict__ rnn_b, float* __restrict__ hn_last,
                          const float* __restrict__ Win, u32* __restrict__ flags, int slot,
                          u16* __restrict__ sm) {
  const long jrowA = (long)(j0 + lr) * H5 + lk;
  const long jrowB = (long)(j0 + 16 + lr) * H5 + lk;
  const int col = lr & 7;

  float wA[4][4], wB[4][4];
  if constexpr (R == 3) {
#pragma unroll
    for (int i = 0; i < 4; ++i)
#pragma unroll
      for (int rr = 0; rr < 4; ++rr) {
        wA[i][rr] = Win[i * 256 + (j0 - 768) + hi * 4 + rr];
        wB[i][rr] = Win[i * 256 + (j0 - 768 + 16) + hi * 4 + rr];
      }
  }

  f32x4 hpA, hpB;
  {
    const float* ha = hn + (long)bcol * H5 + j0 + hi * 4;
#pragma unroll
    for (int rr = 0; rr < 4; ++rr) { hpA[rr] = ha[rr]; hpB[rr] = ha[16 + rr]; }
  }

  for (int t = 0; t < TT; ++t) {
    const u16* hs_r = hs + (t & 1) * (3 * SPL);
    u16* hs_w = hs + ((t & 1) ^ 1) * (3 * SPL);

    stage_h<R>(hs_r, bcol0, sm);
    __syncthreads();

    f32x4 o[2];
    mm_lds<R>(sm, lk, col, W0, W1, W2, jrowA, jrowB, o);

    if constexpr (R == 3) {
      const float* ip = inp_b + t * 4;
      float i0 = ip[0], i1 = ip[1], i2 = ip[2], i3 = ip[3];
#pragma unroll
      for (int rr = 0; rr < 4; ++rr) {
        o[0][rr] += i0 * wA[0][rr] + i1 * wA[1][rr] + i2 * wA[2][rr] + i3 * wA[3][rr];
        o[1][rr] += i0 * wB[0][rr] + i1 * wB[1][rr] + i2 * wB[2][rr] + i3 * wB[3][rr];
      }
    }

    f32x4 hA, hB;
#pragma unroll
    for (int rr = 0; rr < 4; ++rr) {
      hA[rr] = fmaxf(0.0f, 0.9f * hpA[rr] + 0.1f * o[0][rr]);
      hB[rr] = fmaxf(0.0f, 0.9f * hpB[rr] + 0.1f * o[1][rr]);
    }
    hpA = hA; hpB = hB;

    if (act) {
      float* rp = rnn_b + (long)t * H5 + j0 + hi * 4;
      *(f32x4*)rp = hA;
      *(f32x4*)(rp + 16) = hB;
    }

    if (t < TT - 1) {
      if (act) {
        u16x4 sA0, sA1, sA2, sB0, sB1, sB2;
#pragma unroll
        for (int rr = 0; rr < 4; ++rr) {
          float v = hA[rr];
          u16 c0 = f2b(v);  float r1 = v - b2f(c0);
          u16 c1 = f2b(r1); float r2 = r1 - b2f(c1);
          sA0[rr] = c0; sA1[rr] = c1; sA2[rr] = f2b(r2);
          v = hB[rr];
          c0 = f2b(v);  r1 = v - b2f(c0);
          c1 = f2b(r1); r2 = r1 - b2f(c1);
          sB0[rr] = c0; sB1[rr] = c1; sB2[rr] = f2b(r2);
        }
        u16* hw = hs_w + (long)bcol * H5 + j0 + hi * 4;
        st8_sc1(hw, sA0);
        st8_sc1(hw + SPL, sA1);
        st8_sc1(hw + 2 * SPL, sA2);
        st8_sc1(hw + 16, sB0);
        st8_sc1(hw + 16 + SPL, sB1);
        st8_sc1(hw + 16 + 2 * SPL, sB2);
      }
      // shortened barrier: drain -> flag store (no private wait) -> poll
      asm volatile("s_waitcnt vmcnt(0)" ::: "memory");
      __syncthreads();
      if (threadIdx.x == 0) {
        u32 tv = (u32)(t + 1);
        u32* myf = flags + slot;
        asm volatile("global_store_dword %0, %1, off sc1" :: "v"(myf), "v"(tv) : "memory");
        for (;;) {
          u32x4 f0, f1; u32x2 f2;
          asm volatile("global_load_dwordx4 %0, %1, off sc1" : "=v"(f0) : "v"(flags) : "memory");
          asm volatile("global_load_dwordx4 %0, %1, off sc1" : "=v"(f1) : "v"(flags + 4) : "memory");
          asm volatile("global_load_dwordx2 %0, %1, off sc1" : "=v"(f2) : "v"(flags + 8) : "memory");
          asm volatile("s_waitcnt vmcnt(0)" ::: "memory");
          u32 m = umin_(umin_(umin_(f0[0], f0[1]), umin_(f0[2], f0[3])),
                        umin_(umin_(f1[0], f1[1]), umin_(f1[2], f1[3])));
          m = umin_(m, umin_(f2[0], f2[1]));
          if (m >= tv) break;
          __builtin_amdgcn_s_sleep(1);
        }
      }
      __syncthreads();
    } else if (act) {
      float* hl = hn_last + (long)bcol * H5 + j0 + hi * 4;
      *(f32x4*)hl = hA;
      *(f32x4*)(hl + 16) = hB;
    }
  }
}

__global__ void __launch_bounds__(256, 1)
rnn_pers(const float* __restrict__ inp, const float* __restrict__ hn,
         const u16* __restrict__ W0, const u16* __restrict__ W1, const u16* __restrict__ W2,
         u16* __restrict__ hs, float* __restrict__ rnn, float* __restrict__ hn_last,
         const float* __restrict__ Win, u32* __restrict__ cnt) {
  __shared__ u16 smh[19008];  // worst case (R0): 3q x 24 x (256+8) u16 = 38016 B
  const int tid = threadIdx.x, bx = blockIdx.x;
  const int g = bx & 7, slot = bx >> 3;
  const int lane = tid & 63, w = tid >> 6;
  const int lr = lane & 15, hi = lane >> 4, lk = hi * 8;
  const int bcol0 = g * 8;
  const int bcol = bcol0 + (lr & 7);   // lanes 8-15 duplicate cols 0-7 (discarded)
  const bool act = lr < 8;
  const int j0 = slot * 128 + w * 32;  // wave's two j-tiles: j0, j0+16
  u32* flags = cnt + 128 + g * 32;
  float* rnn_b = rnn + (long)bcol * TT * H5;
  const float* inp_b = inp + (long)bcol * TT * 4;
  switch (slot >> 1) {
    case 0: pers_loop<0>(j0, bcol, act, hi, lk, lr, bcol0, inp_b, hn, W0, W1, W2, hs, rnn_b, hn_last, Win, flags, slot, smh); break;
    case 1: pers_loop<1>(j0, bcol, act, hi, lk, lr, bcol0, inp_b, hn, W0, W1, W2, hs, rnn_b, hn_last, Win, flags, slot, smh); break;
    case 2: pers_loop<2>(j0, bcol, act, hi, lk, lr, bcol0, inp_b, hn, W0, W1, W2, hs, rnn_b, hn_last, Win, flags, slot, smh); break;
    case 3: pers_loop<3>(j0, bcol, act, hi, lk, lr, bcol0, inp_b, hn, W0, W1, W2, hs, rnn_b, hn_last, Win, flags, slot, smh); break;
    default: pers_loop<4>(j0, bcol, act, hi, lk, lr, bcol0, inp_b, hn, W0, W1, W2, hs, rnn_b, hn_last, Win, flags, slot, smh); break;
  }
}

// ---------------- fallback: one kernel per timestep (plain loads) -----------
template <int R>
__device__ void step_one(int t, int j0, int bcol, bool act, int hi, int lk, int lr,
                         const float* __restrict__ inp_b, const float* __restrict__ hn,
                         const u16* __restrict__ W0, const u16* __restrict__ W1,
                         const u16* __restrict__ W2, u16* __restrict__ hs,
                         float* __restrict__ rnn, float* __restrict__ rnn_b,
                         float* __restrict__ hn_last, const float* __restrict__ Win) {
  const long jrowA = (long)(j0 + lr) * H5 + lk;
  const long jrowB = (long)(j0 + 16 + lr) * H5 + lk;
  const u16* hs_r = hs + (t & 1) * (3 * SPL);
  u16* hs_w = hs + ((t & 1) ^ 1) * (3 * SPL);

  f32x4 acc[2][6];
#pragma unroll
  for (int tt = 0; tt < 2; ++tt)
#pragma unroll
    for (int s = 0; s < 6; ++s) acc[tt][s] = {0.f, 0.f, 0.f, 0.f};
#pragma unroll
  for (int q = 0; q < 3; ++q) {
    if (RC<R>::nch[q] > 0) {
      const int kbq = RC<R>::kb[q];
      const u16* hb = hs_r + (long)bcol * H5 + kbq + lk;
#pragma unroll
      for (int c = 0; c < RC<R>::nch[q]; ++c) {
        v8bf B0 = *(const v8bf*)(hb + c * 32);
        v8bf B1 = *(const v8bf*)(hb + SPL + c * 32);
        v8bf B2 = *(const v8bf*)(hb + 2 * SPL + c * 32);
        long oA = jrowA + kbq + c * 32, oB = jrowB + kbq + c * 32;
        v8bf a0 = *(const v8bf*)(W0 + oA);
        v8bf a1 = *(const v8bf*)(W1 + oA);
        v8bf a2 = *(const v8bf*)(W2 + oA);
        v8bf b0 = *(const v8bf*)(W0 + oB);
        v8bf b1 = *(const v8bf*)(W1 + oB);
        v8bf b2 = *(const v8bf*)(W2 + oB);
        acc[0][0] = MFMA(a0, B0, acc[0][0]);
        acc[1][0] = MFMA(b0, B0, acc[1][0]);
        acc[0][1] = MFMA(a0, B1, acc[0][1]);
        acc[1][1] = MFMA(b0, B1, acc[1][1]);
        acc[0][2] = MFMA(a0, B2, acc[0][2]);
        acc[1][2] = MFMA(b0, B2, acc[1][2]);
        acc[0][3] = MFMA(a1, B0, acc[0][3]);
        acc[1][3] = MFMA(b1, B0, acc[1][3]);
        acc[0][4] = MFMA(a1, B1, acc[0][4]);
        acc[1][4] = MFMA(b1, B1, acc[1][4]);
        acc[0][5] = MFMA(a2, B0, acc[0][5]);
        acc[1][5] = MFMA(b2, B0, acc[1][5]);
      }
    }
  }
  f32x4 o[2];
#pragma unroll
  for (int tt = 0; tt < 2; ++tt)
#pragma unroll
    for (int rr = 0; rr < 4; ++rr)
      o[tt][rr] = ((acc[tt][0][rr] + acc[tt][3][rr]) + (acc[tt][1][rr] + acc[tt][4][rr])) +
                  (acc[tt][2][rr] + acc[tt][5][rr]);

  if constexpr (R == 3) {
    const float* ip = inp_b + t * 4;
    float i0 = ip[0], i1 = ip[1], i2 = ip[2], i3 = ip[3];
#pragma unroll
    for (int rr = 0; rr < 4; ++rr) {
      o[0][rr] += i0 * Win[0 * 256 + (j0 - 768) + hi * 4 + rr] +
                  i1 * Win[1 * 256 + (j0 - 768) + hi * 4 + rr] +
                  i2 * Win[2 * 256 + (j0 - 768) + hi * 4 + rr] +
                  i3 * Win[3 * 256 + (j0 - 768) + hi * 4 + rr];
      o[1][rr] += i0 * Win[0 * 256 + (j0 - 768 + 16) + hi * 4 + rr] +
                  i1 * Win[1 * 256 + (j0 - 768 + 16) + hi * 4 + rr] +
                  i2 * Win[2 * 256 + (j0 - 768 + 16) + hi * 4 + rr] +
                  i3 * Win[3 * 256 + (j0 - 768 + 16) + hi * 4 + rr];
    }
  }

  f32x4 hpA, hpB;
  {
    const float* ha = (t == 0) ? (hn + (long)bcol * H5 + j0 + hi * 4)
                               : (rnn + ((long)bcol * TT + (t - 1)) * H5 + j0 + hi * 4);
#pragma unroll
    for (int rr = 0; rr < 4; ++rr) { hpA[rr] = ha[rr]; hpB[rr] = ha[16 + rr]; }
  }
  f32x4 hA, hB;
#pragma unroll
  for (int rr = 0; rr < 4; ++rr) {
    hA[rr] = fmaxf(0.0f, 0.9f * hpA[rr] + 0.1f * o[0][rr]);
    hB[rr] = fmaxf(0.0f, 0.9f * hpB[rr] + 0.1f * o[1][rr]);
  }
  if (act) {
    float* rp = rnn_b + (long)t * H5 + j0 + hi * 4;
    *(f32x4*)rp = hA;
    *(f32x4*)(rp + 16) = hB;
    if (t < TT - 1) {
      u16x4 sA0, sA1, sA2, sB0, sB1, sB2;
#pragma unroll
      for (int rr = 0; rr < 4; ++rr) {
        float v = hA[rr];
        u16 c0 = f2b(v);  float r1 = v - b2f(c0);
        u16 c1 = f2b(r1); float r2 = r1 - b2f(c1);
        sA0[rr] = c0; sA1[rr] = c1; sA2[rr] = f2b(r2);
        v = hB[rr];
        c0 = f2b(v);  r1 = v - b2f(c0);
        c1 = f2b(r1); r2 = r1 - b2f(c1);
        sB0[rr] = c0; sB1[rr] = c1; sB2[rr] = f2b(r2);
      }
      u16* hw = hs_w + (long)bcol * H5 + j0 + hi * 4;
      *(u64*)hw = *(u64*)&sA0;
      *(u64*)(hw + SPL) = *(u64*)&sA1;
      *(u64*)(hw + 2 * SPL) = *(u64*)&sA2;
      *(u64*)(hw + 16) = *(u64*)&sB0;
      *(u64*)(hw + 16 + SPL) = *(u64*)&sB1;
      *(u64*)(hw + 16 + 2 * SPL) = *(u64*)&sB2;
    } else {
      float* hl = hn_last + (long)bcol * H5 + j0 + hi * 4;
      *(f32x4*)hl = hA;
      *(f32x4*)(hl + 16) = hB;
    }
  }
}

__global__ void __launch_bounds__(256, 1)
rnn_step(const float* __restrict__ inp, const float* __restrict__ hn,
         const u16* __restrict__ W0, const u16* __restrict__ W1, const u16* __restrict__ W2,
         u16* __restrict__ hs, float* __restrict__ rnn, float* __restrict__ hn_last,
         const float* __restrict__ Win, int t) {
  const int tid = threadIdx.x, bx = blockIdx.x;
  const int g = bx & 7, slot = bx >> 3;
  const int lane = tid & 63, w = tid >> 6;
  const int lr = lane & 15, hi = lane >> 4, lk = hi * 8;
  const int bcol = g * 8 + (lr & 7);
  const bool act = lr < 8;
  const int j0 = slot * 128 + w * 32;
  float* rnn_b = rnn + (long)bcol * TT * H5;
  const float* inp_b = inp + (long)bcol * TT * 4;
  switch (slot >> 1) {
    case 0: step_one<0>(t, j0, bcol, act, hi, lk, lr, inp_b, hn, W0, W1, W2, hs, rnn, rnn_b, hn_last, Win); break;
    case 1: step_one<1>(t, j0, bcol, act, hi, lk, lr, inp_b, hn, W0, W1, W2, hs, rnn, rnn_b, hn_last, Win); break;
    case 2: step_one<2>(t, j0, bcol, act, hi, lk, lr, inp_b, hn, W0, W1, W2, hs, rnn, rnn_b, hn_last, Win); break;
    case 3: step_one<3>(t, j0, bcol, act, hi, lk, lr, inp_b, hn, W0, W1, W2, hs, rnn, rnn_b, hn_last, Win); break;
    default: step_one<4>(t, j0, bcol, act, hi, lk, lr, inp_b, hn, W0, W1, W2, hs, rnn, rnn_b, hn_last, Win); break;
  }
}

extern "C" void kernel_launch(void* const* d_in, const int* in_sizes, int n_in,
                              void* d_out, int out_size, void* d_ws, size_t ws_size,
                              hipStream_t stream) {
  const float* inp        = (const float*)d_in[0];
  const float* hn         = (const float*)d_in[1];
  const float* w_str2snr  = (const float*)d_in[3];
  const float* w_m12m1    = (const float*)d_in[4];
  const float* w_m12str   = (const float*)d_in[5];
  const float* w_thal2m1  = (const float*)d_in[6];
  const float* w_m12thal  = (const float*)d_in[7];
  const float* w_thal2str = (const float*)d_in[8];
  const float* w_str2stn  = (const float*)d_in[9];
  const float* w_snr2thal = (const float*)d_in[11];
  const float* inp_weight = (const float*)d_in[12];
  const float* mean_b     = (const float*)d_in[14];
  const float* std_b      = (const float*)d_in[16];
  const float* fixedw     = (const float*)d_in[18];

  char* ws = (char*)d_ws;
  u16* W0 = (u16*)(ws + OFF_W0);
  u16* W1 = (u16*)(ws + OFF_W1);
  u16* W2 = (u16*)(ws + OFF_W2);
  u16* hsb = (u16*)(ws + OFF_HS);
  float* Win = (float*)(ws + OFF_WIN);
  u32* cnt = (u32*)(ws + OFF_CNT);

  float* out = (float*)d_out;
  float* rnn = out + 65536;
  float* hnl = out + 65536 + 41943040;

  build_w<<<6400, 256, 0, stream>>>(w_str2snr, w_m12m1, w_m12str, w_thal2m1, w_m12thal,
                                    w_thal2str, w_str2stn, w_snr2thal, fixedw, W0, W1, W2);
  build_misc<<<581, 256, 0, stream>>>(hn, inp_weight, mean_b, std_b, out, hsb, Win);

  bool coop_ok = (ws_size >= (size_t)OFF_CNT + 2048);
  hipError_t e = hipErrorUnknown;
  if (coop_ok) {
    hipMemsetAsync(cnt, 0, 1536, stream);
    void* args[] = {(void*)&inp, (void*)&hn, (void*)&W0, (void*)&W1, (void*)&W2, (void*)&hsb,
                    (void*)&rnn, (void*)&hnl, (void*)&Win, (void*)&cnt};
    e = hipLaunchCooperativeKernel((const void*)rnn_pers, dim3(NBLK), dim3(256),
                                   args, 0, stream);
  }
  if (e != hipSuccess) {
    for (int t = 0; t < TT; ++t)
      rnn_step<<<NBLK, 256, 0, stream>>>(inp, hn, W0, W1, W2, hsb, rnn, hnl, Win, t);
  }
}